// Round 15
// baseline (73.338 us; speedup 1.0000x reference)
//
#include <hip/hip_runtime.h>
#include <stdint.h>

#define BB 64
#define CC 3
#define HH 512
#define WW 512
#define TLW 32
#define TLH 16
#define NTPB 512  // tiles per batch: (512/32)*(512/16)
#define MAXBH 40
#define MAXBW 44
#define PLST 44  // plane row stride (dwords)

typedef float f32x4 __attribute__((ext_vector_type(4)));

__device__ __forceinline__ void pix2in(float x, float y,
                                       float cs, float sn, float tx, float ty,
                                       float& ix, float& iy)
{
    float gx = (2.0f * x + 1.0f) * (1.0f / (float)WW) - 1.0f;
    float gy = (2.0f * y + 1.0f) * (1.0f / (float)HH) - 1.0f;
    float gxt = cs * gx - sn * gy + tx;
    float gyt = sn * gx + cs * gy + ty;
    ix = ((gxt + 1.0f) * (float)WW - 1.0f) * 0.5f;
    iy = ((gyt + 1.0f) * (float)HH - 1.0f) * 0.5f;
}

// ws layout: float prm[64*4] (cs,sn,tx,ty per batch), then uint32 desc[64*512]
__global__ __launch_bounds__(256) void warp_setup(
    const float* __restrict__ rot, const float* __restrict__ trans,
    const float* __restrict__ scale, float* __restrict__ ws)
{
    const int i = blockIdx.x * 256 + threadIdx.x;   // 0..32767 = b*512+t
    const int b = i >> 9, t = i & 511;
    const float r = rot[b];
    const float inv_s = 1.0f / scale[b];
    const float cs = cosf(r) * inv_s;
    const float sn = sinf(r) * inv_s;
    const float tx = trans[2 * b], ty = trans[2 * b + 1];
    if (t == 0)
        reinterpret_cast<float4*>(ws)[b] = make_float4(cs, sn, tx, ty);

    const int oy0 = (t >> 4) * TLH;
    const int ox0 = (t & 15) * TLW;
    float ixa, iya, ixb, iyb, ixc, iyc, ixd, iyd;
    pix2in((float)ox0,             (float)oy0,             cs, sn, tx, ty, ixa, iya);
    pix2in((float)(ox0 + TLW - 1), (float)oy0,             cs, sn, tx, ty, ixb, iyb);
    pix2in((float)ox0,             (float)(oy0 + TLH - 1), cs, sn, tx, ty, ixc, iyc);
    pix2in((float)(ox0 + TLW - 1), (float)(oy0 + TLH - 1), cs, sn, tx, ty, ixd, iyd);
    const float minix = fminf(fminf(ixa, ixb), fminf(ixc, ixd));
    const float maxix = fmaxf(fmaxf(ixa, ixb), fmaxf(ixc, ixd));
    const float miniy = fminf(fminf(iya, iyb), fminf(iyc, iyd));
    const float maxiy = fmaxf(fmaxf(iya, iyb), fmaxf(iyc, iyd));
    const int bx0 = (int)floorf(minix) - 1;
    const int bx1 = (int)floorf(maxix) + 2;
    const int by0 = (int)floorf(miniy) - 1;
    const int by1 = (int)floorf(maxiy) + 2;
    int bx0c = bx0 & ~3;
    const int bw = bx1 - bx0c + 1;
    const int bh = by1 - by0 + 1;

    const uint32_t fit      = (bw <= MAXBW && bh <= MAXBH) ? 1u : 0u;
    const uint32_t interior = (bx0c >= 0 && bx1 < WW && by0 >= 0 && by1 < HH) ? 1u : 0u;
    const int bx0s = min(max(bx0c, -2048), 2047);
    const int by0s = min(max(by0,  -2048), 2047);
    const int bhs  = min(bh, 63);
    const uint32_t desc = ((uint32_t)bx0s & 0xFFFu)
                        | (((uint32_t)by0s & 0xFFFu) << 12)
                        | ((uint32_t)bhs << 24)
                        | (fit << 30) | (interior << 31);
    reinterpret_cast<uint32_t*>(ws)[256 + i] = desc;
}

template <bool INTERIOR>
__device__ __forceinline__ void compute_store(
    const float* __restrict__ pl, float* __restrict__ outb,
    int tid, int ox0, int oy0, int bx0c, int by0,
    float cs, float sn, float tpx, float tpy, long plane)
{
    const int ry = tid >> 5;             // 0..7
    const int xp = tid & 31;             // 0..31 (lane stride 1 in x)
    const int ox = ox0 + xp;

    float ix0, iy0;
    pix2in((float)ox, (float)(oy0 + ry), cs, sn, tpx, tpy, ix0, iy0);

    #pragma unroll
    for (int h = 0; h < 2; ++h) {
        // second half: +8 output rows; affine: d(ix)/dy = -sn, d(iy)/dy = +cs
        const float ix = fmaf((float)(8 * h), -sn, ix0);
        const float iy = fmaf((float)(8 * h),  cs, iy0);
        const float x0f = floorf(ix), y0f = floorf(iy);
        const float wx1 = ix - x0f,  wy1 = iy - y0f;
        const float wx0 = 1.0f - wx1, wy0 = 1.0f - wy1;
        const int x0 = (int)x0f, y0 = (int)y0f;

        float w00 = wy0 * wx0, w01 = wy0 * wx1, w10 = wy1 * wx0, w11 = wy1 * wx1;
        if (!INTERIOR) {
            const int x1 = x0 + 1, y1 = y0 + 1;
            const float vx0 = (x0 >= 0 && x0 < WW) ? 1.0f : 0.0f;
            const float vx1 = (x1 >= 0 && x1 < WW) ? 1.0f : 0.0f;
            const float vy0 = (y0 >= 0 && y0 < HH) ? 1.0f : 0.0f;
            const float vy1 = (y1 >= 0 && y1 < HH) ? 1.0f : 0.0f;
            w00 *= vy0 * vx0; w01 *= vy0 * vx1; w10 *= vy1 * vx0; w11 *= vy1 * vx1;
        }

        const int idx = (y0 - by0) * PLST + (x0 - bx0c);   // margin guarantees in-range
        const float* pb = pl + idx;
        const int oy = oy0 + ry + 8 * h;
        const long ob = (long)oy * WW + ox;
        #pragma unroll
        for (int c = 0; c < CC; ++c) {
            const float* pc = pb + c * (MAXBH * PLST);     // channel via byte immediate
            const float v = w00 * pc[0] + w01 * pc[1]
                          + w10 * pc[PLST] + w11 * pc[PLST + 1];
            __builtin_nontemporal_store(v, outb + c * plane + ob);
        }
    }
}

__global__ __launch_bounds__(256) void warp_tiled(
    const float* __restrict__ img, const float* __restrict__ ws,
    float* __restrict__ out)
{
    __shared__ __align__(16) float pl[CC][MAXBH][PLST];   // 21.1 KB -> 7 blocks/CU

    // 32768 blocks; XCD chunk swizzle: each XCD owns 4096 consecutive = 8 whole batches
    const int g   = blockIdx.x;
    const int swz = (g & 7) * ((BB * NTPB) / 8) + (g >> 3);
    const int b   = swz >> 9;
    const int t   = swz & 511;
    const int oy0 = (t >> 4) * TLH;
    const int ox0 = (t & 15) * TLW;

    const float4 p = reinterpret_cast<const float4*>(ws)[b];
    const float cs = p.x, sn = p.y, tpx = p.z, tpy = p.w;
    const uint32_t desc = reinterpret_cast<const uint32_t*>(ws)[256 + swz];
    const int  bx0c     = ((int)(desc << 20)) >> 20;
    const int  by0      = ((int)(desc << 8))  >> 20;
    const int  bh       = (desc >> 24) & 63;
    const bool fit      = (desc >> 30) & 1;
    const bool interior = (desc >> 31) & 1;

    const long plane = (long)HH * WW;
    const float* imb = img + (long)b * CC * plane;
    float* outb      = out + (long)b * CC * plane;
    const int tid = threadIdx.x;

    if (fit) {
        const int q  = tid >> 4;          // 0..15 row group
        const int ql = tid & 15;          // 11 active lanes cover 44 cols
        if (ql < 11) {
            const int xb = ql * 4;        // col offset within bbox, 16B-aligned slot
            if (interior && (bx0c + MAXBW - 1 < WW)) {
                for (int r = q; r < bh; r += 16) {
                    const float* pr = imb + (long)(by0 + r) * WW + (bx0c + xb);
                    const f32x4 a = *reinterpret_cast<const f32x4*>(pr);
                    const f32x4 bv = *reinterpret_cast<const f32x4*>(pr + plane);
                    const f32x4 cv = *reinterpret_cast<const f32x4*>(pr + 2 * plane);
                    *reinterpret_cast<f32x4*>(&pl[0][r][xb]) = a;    // contiguous b128
                    *reinterpret_cast<f32x4*>(&pl[1][r][xb]) = bv;
                    *reinterpret_cast<f32x4*>(&pl[2][r][xb]) = cv;
                }
            } else {
                for (int r = q; r < bh; r += 16) {
                    const int grow = by0 + r;
                    const bool rowok = (grow >= 0) && (grow < HH);
                    const float* pr = imb + (long)grow * WW;
                    f32x4 a = {0.f, 0.f, 0.f, 0.f}, bv = a, cv = a;
                    #pragma unroll
                    for (int k = 0; k < 4; ++k) {
                        const int gcol = bx0c + xb + k;
                        if (rowok && gcol >= 0 && gcol < WW) {
                            a[k]  = pr[gcol];
                            bv[k] = pr[(long)gcol + plane];
                            cv[k] = pr[(long)gcol + 2 * plane];
                        }
                    }
                    *reinterpret_cast<f32x4*>(&pl[0][r][xb]) = a;
                    *reinterpret_cast<f32x4*>(&pl[1][r][xb]) = bv;
                    *reinterpret_cast<f32x4*>(&pl[2][r][xb]) = cv;
                }
            }
        }
        __syncthreads();

        if (interior)
            compute_store<true >(&pl[0][0][0], outb, tid, ox0, oy0, bx0c, by0, cs, sn, tpx, tpy, plane);
        else
            compute_store<false>(&pl[0][0][0], outb, tid, ox0, oy0, bx0c, by0, cs, sn, tpx, tpy, plane);
    } else {
        // ---- fallback: direct global gather (never taken for scale=1) ----
        #pragma unroll
        for (int k = 0; k < 2; ++k) {
            const int pidx = tid + k * 256;
            const int py = pidx >> 5;      // 0..15
            const int px = pidx & 31;
            const int ox = ox0 + px, oy = oy0 + py;

            float ix, iy;
            pix2in((float)ox, (float)oy, cs, sn, tpx, tpy, ix, iy);
            const float x0f = floorf(ix), y0f = floorf(iy);
            const float wx1 = ix - x0f,  wy1 = iy - y0f;
            const int x0 = (int)x0f, y0 = (int)y0f;
            const int x1 = x0 + 1,  y1 = y0 + 1;

            const float vx0 = (x0 >= 0 && x0 < WW) ? 1.0f : 0.0f;
            const float vx1 = (x1 >= 0 && x1 < WW) ? 1.0f : 0.0f;
            const float vy0 = (y0 >= 0 && y0 < HH) ? 1.0f : 0.0f;
            const float vy1 = (y1 >= 0 && y1 < HH) ? 1.0f : 0.0f;

            const int x0c = min(max(x0, 0), WW - 1);
            const int x1c = min(max(x1, 0), WW - 1);
            const int y0c = min(max(y0, 0), HH - 1);
            const int y1c = min(max(y1, 0), HH - 1);

            const float w00 = (1.0f - wy1) * (1.0f - wx1) * vy0 * vx0;
            const float w01 = (1.0f - wy1) * wx1          * vy0 * vx1;
            const float w10 = wy1          * (1.0f - wx1) * vy1 * vx0;
            const float w11 = wy1          * wx1          * vy1 * vx1;

            const int o00 = y0c * WW + x0c, o01 = y0c * WW + x1c;
            const int o10 = y1c * WW + x0c, o11 = y1c * WW + x1c;
            const int ob = oy * WW + ox;
            #pragma unroll
            for (int c = 0; c < CC; ++c) {
                const float* pc = imb + (long)c * plane;
                const float v = w00 * pc[o00] + w01 * pc[o01]
                              + w10 * pc[o10] + w11 * pc[o11];
                __builtin_nontemporal_store(v, &outb[(long)c * plane + ob]);
            }
        }
    }
}

extern "C" void kernel_launch(void* const* d_in, const int* in_sizes, int n_in,
                              void* d_out, int out_size, void* d_ws, size_t ws_size,
                              hipStream_t stream) {
    const float* img   = (const float*)d_in[0];
    const float* rot   = (const float*)d_in[1];
    const float* trans = (const float*)d_in[2];
    const float* scale = (const float*)d_in[3];
    float* out = (float*)d_out;
    float* ws  = (float*)d_ws;

    warp_setup<<<dim3(BB * NTPB / 256), 256, 0, stream>>>(rot, trans, scale, ws);
    warp_tiled<<<dim3(BB * NTPB), 256, 0, stream>>>(img, ws, out);
}